// Round 1
// 1732.652 us; speedup vs baseline: 1.6522x; 1.6522x over previous
//
#include <hip/hip_runtime.h>
#include <math.h>

#define B_ 4
#define L_ 1024
#define DM 1024
#define DI 2048
#define DS 16
#define DC 4
#define NROWS (B_*L_)   // 4096
#define CH 32           // scan chunk length
#define NC (L_/CH)      // 32 chunks per row

__device__ __forceinline__ float sigmoidf_(float x){ return 1.f/(1.f+__expf(-x)); }
__device__ __forceinline__ float softplusf_(float x){ return fmaxf(x,0.f) + log1pf(__expf(-fabsf(x))); }

__device__ __forceinline__ void load16(const float* __restrict__ p, float* r){
  float4 v0 = *(const float4*)(p);
  float4 v1 = *(const float4*)(p+4);
  float4 v2 = *(const float4*)(p+8);
  float4 v3 = *(const float4*)(p+12);
  r[0]=v0.x; r[1]=v0.y; r[2]=v0.z; r[3]=v0.w;
  r[4]=v1.x; r[5]=v1.y; r[6]=v1.z; r[7]=v1.w;
  r[8]=v2.x; r[9]=v2.y; r[10]=v2.z; r[11]=v2.w;
  r[12]=v3.x; r[13]=v3.y; r[14]=v3.z; r[15]=v3.w;
}
__device__ __forceinline__ void store16(float* __restrict__ p, const float* r){
  float4 v0 = {r[0],r[1],r[2],r[3]};
  float4 v1 = {r[4],r[5],r[6],r[7]};
  float4 v2 = {r[8],r[9],r[10],r[11]};
  float4 v3 = {r[12],r[13],r[14],r[15]};
  *(float4*)(p)    = v0;
  *(float4*)(p+4)  = v1;
  *(float4*)(p+8)  = v2;
  *(float4*)(p+12) = v3;
}

__global__ void zero_f32(float* __restrict__ p, int n){
  int i = blockIdx.x*256 + threadIdx.x;
  if (i < n) p[i] = 0.f;
}

// C[M,N] = A[M,K] @ B[N,K]^T   (NT GEMM, fp32)
// EPI: 0 = plain store, 1 = softplus(v + bias[c]), 2 = dual store (outputs + out_traj), 3 = atomicAdd (split-K)
template<int TM, int TN, int BK, int EPI>
__global__ __launch_bounds__(256) void gemm_nt(
    const float* __restrict__ A, const float* __restrict__ Bw,
    float* __restrict__ C, float* __restrict__ C2,
    const float* __restrict__ bias,
    int M, int N, int K, int lda, int ldc)
{
  static_assert(TM*BK == 1024 && TN*BK == 1024, "one float4 per thread per tile");
  constexpr int MT = TM/16, NT = TN/16;
  __shared__ float As[BK][TM];
  __shared__ float Bs[BK][TN];
  const int tid = threadIdx.x;
  const int tx = tid & 15, ty = tid >> 4;
  const int m0 = blockIdx.y * TM, n0 = blockIdx.x * TN;
  const int kchunk = K / (int)gridDim.z;
  const int kbeg = blockIdx.z * kchunk;

  constexpr int K4 = BK/4;
  const int lrow = tid / K4;
  const int lk4  = (tid % K4) * 4;

  float acc[MT][NT];
  #pragma unroll
  for (int i=0;i<MT;++i)
    #pragma unroll
    for (int j=0;j<NT;++j) acc[i][j]=0.f;

  const int arow = m0 + lrow;
  const int brow = n0 + lrow;
  const float* Aptr = A + (size_t)arow*lda + lk4;
  const float* Bptr = Bw + (size_t)brow*K  + lk4;
  const bool bvalid = (brow < N);

  for (int k0 = kbeg; k0 < kbeg + kchunk; k0 += BK) {
    float4 av = *(const float4*)(Aptr + k0);
    float4 bv = bvalid ? *(const float4*)(Bptr + k0) : make_float4(0.f,0.f,0.f,0.f);
    __syncthreads();
    As[lk4+0][lrow]=av.x; As[lk4+1][lrow]=av.y; As[lk4+2][lrow]=av.z; As[lk4+3][lrow]=av.w;
    Bs[lk4+0][lrow]=bv.x; Bs[lk4+1][lrow]=bv.y; Bs[lk4+2][lrow]=bv.z; Bs[lk4+3][lrow]=bv.w;
    __syncthreads();
    #pragma unroll
    for (int kk=0;kk<BK;++kk){
      float a[MT], b[NT];
      #pragma unroll
      for (int i=0;i<MT;++i) a[i]=As[kk][ty*MT+i];
      #pragma unroll
      for (int j=0;j<NT;++j) b[j]=Bs[kk][tx*NT+j];
      #pragma unroll
      for (int i=0;i<MT;++i)
        #pragma unroll
        for (int j=0;j<NT;++j)
          acc[i][j] = fmaf(a[i], b[j], acc[i][j]);
    }
  }

  #pragma unroll
  for (int i=0;i<MT;++i){
    int r  = m0 + ty*MT + i;
    int bb = r >> 10;          // r / L_
    int tt = r & (L_-1);
    #pragma unroll
    for (int j=0;j<NT;++j){
      int c = n0 + tx*NT + j;
      float v = acc[i][j];
      if (EPI==0){
        if (c < N) C[(size_t)r*ldc + c] = v;
      } else if (EPI==1){
        C[(size_t)r*ldc + c] = softplusf_(v + bias[c]);
      } else if (EPI==2){
        C[(size_t)r*ldc + c] = v;
        C2[((size_t)tt*B_ + bb)*(size_t)N + c] = v;
      } else { // 3
        if (c < N) atomicAdd(&C[(size_t)r*ldc + c], v);
      }
    }
  }
}

// xc[b,t,d] = silu(sum_j xi[b,t-3+j,d]*conv_w[d,j] + conv_b[d]); also emit conv_traj[t+1]
__global__ __launch_bounds__(256) void conv_silu(
    const float* __restrict__ xz, const float* __restrict__ conv_w,
    const float* __restrict__ conv_b, float* __restrict__ xc,
    float* __restrict__ conv_traj)
{
  int idx = blockIdx.x*256 + threadIdx.x;        // over NROWS*DI (exact multiple)
  int d = idx & (DI-1);
  int m = idx >> 11;                              // DI = 2^11
  int t = m & (L_-1), b = m >> 10;
  float v0 = (t>=3) ? xz[(size_t)(m-3)*2*DI + d] : 0.f;
  float v1 = (t>=2) ? xz[(size_t)(m-2)*2*DI + d] : 0.f;
  float v2 = (t>=1) ? xz[(size_t)(m-1)*2*DI + d] : 0.f;
  float v3 =          xz[(size_t) m   *2*DI + d];
  float4 cw = *(const float4*)&conv_w[d*4];
  float s = v0*cw.x + v1*cw.y + v2*cw.z + v3*cw.w + conv_b[d];
  xc[(size_t)m*DI + d] = s * sigmoidf_(s);
  float4 pk; pk.x=v0; pk.y=v1; pk.z=v2; pk.w=v3;
  *(float4*)&conv_traj[((size_t)(t+1)*B_ + b)*DI*DC + (size_t)d*DC] = pk;
}

// ---- chunked parallel scan --------------------------------------------------
// st_t[s] = st_{t-1}[s]*exp(dt_t*A[s]) + dt_t*xc_t*B_t[s]  is a linear recurrence.
// Phase 1: per (b,d,chunk) compute S = sum(dt) over chunk and zero-init local final Q[16].
//          (chunk transition multiplier is exp(A[s]*S) since prod of exps = exp of sum)
// Phase 2: per (b,d,s) combine 32 chunk summaries sequentially; rewrite Q in place
//          with each chunk's START state.
// Phase 3: per (b,d,chunk) replay chunk from its start state, writing ssm_traj + gated y.

__global__ __launch_bounds__(256) void scan_phase1(
    const float* __restrict__ xz,      // dt in cols [0,2048), stride 4096
    const float* __restrict__ xc,
    const float* __restrict__ xdb,     // [4096][96]; B at +64
    const float* __restrict__ A_log,
    float* __restrict__ Ssum,          // [B_*NC][DI]
    float* __restrict__ Q)             // [B_*NC][DI][DS]
{
  int idx = blockIdx.x*256 + threadIdx.x;   // b*NC*DI + c*DI + d
  int d  = idx & (DI-1);
  int bc = idx >> 11;
  int c  = bc & (NC-1);
  int b  = bc >> 5;                          // NC = 32

  float Ac[DS]; load16(A_log + (size_t)d*DS, Ac);
  #pragma unroll
  for (int s=0;s<DS;++s) Ac[s] = -__expf(Ac[s]);

  float q[DS];
  #pragma unroll
  for (int s=0;s<DS;++s) q[s] = 0.f;
  float S = 0.f;

  const size_t mbase = (size_t)b*L_ + (size_t)c*CH;
  for (int t=0;t<CH;++t){
    size_t m = mbase + t;
    float dtv = xz[m*2*DI + d];
    float xcv = xc[m*DI + d];
    float Bm[DS]; load16(xdb + m*96 + 64, Bm);
    float dtxc = dtv * xcv;
    S += dtv;
    #pragma unroll
    for (int s=0;s<DS;++s) q[s] = fmaf(q[s], __expf(dtv*Ac[s]), dtxc*Bm[s]);
  }
  size_t off = (size_t)bc*DI + d;
  Ssum[off] = S;
  store16(Q + off*DS, q);
}

__global__ __launch_bounds__(256) void scan_phase2(
    const float* __restrict__ Ssum,
    float* __restrict__ Q,             // in: chunk-local finals; out: chunk-start states
    const float* __restrict__ A_log)
{
  int idx = blockIdx.x*256 + threadIdx.x;   // b*DI*DS + d*DS + s  (B_*DI*DS = 131072)
  int s = idx & (DS-1);
  int d = (idx >> 4) & (DI-1);
  int b = idx >> 15;                        // DI*DS = 2^15
  float Ac = -__expf(A_log[(size_t)d*DS + s]);
  float st = 0.f;
  for (int c=0;c<NC;++c){
    size_t off = ((size_t)b*NC + c)*DI + d;
    float Sv = Ssum[off];
    float* qp = Q + off*DS + s;
    float q = *qp;
    *qp = st;                               // start state of chunk c
    st = fmaf(st, __expf(Ac*Sv), q);
  }
}

__global__ __launch_bounds__(256) void scan_phase3(
    const float* __restrict__ xz,      // dt cols [0,2048), z cols [2048,4096), stride 4096
    float* __restrict__ xc_yg,         // in: xc, out: y*silu(z)
    const float* __restrict__ xdb,     // [4096][96]; B at +64, C at +80
    const float* __restrict__ A_log, const float* __restrict__ Dp,
    const float* __restrict__ Qs,      // chunk-start states [B_*NC][DI][DS]
    float* __restrict__ ssm_traj)
{
  int idx = blockIdx.x*256 + threadIdx.x;   // b*NC*DI + c*DI + d
  int d  = idx & (DI-1);
  int bc = idx >> 11;
  int c  = bc & (NC-1);
  int b  = bc >> 5;

  float Ac[DS]; load16(A_log + (size_t)d*DS, Ac);
  #pragma unroll
  for (int s=0;s<DS;++s) Ac[s] = -__expf(Ac[s]);
  float Dv = Dp[d];

  float st[DS]; load16(Qs + ((size_t)bc*DI + d)*DS, st);

  for (int t=0;t<CH;++t){
    int tt = c*CH + t;
    size_t m = (size_t)b*L_ + tt;
    float xcv = xc_yg[m*DI + d];
    float dtv = xz[m*2*DI + d];
    float zv  = xz[m*2*DI + DI + d];
    float Bm[DS]; load16(xdb + m*96 + 64, Bm);
    float Cm[DS]; load16(xdb + m*96 + 80, Cm);
    float dtxc = dtv * xcv;
    float y = 0.f;
    #pragma unroll
    for (int s=0;s<DS;++s){
      st[s] = fmaf(st[s], __expf(dtv*Ac[s]), dtxc*Bm[s]);
      y = fmaf(st[s], Cm[s], y);
    }
    float* sp = ssm_traj + ((size_t)(tt+1)*B_ + b)*DI*DS + (size_t)d*DS;
    store16(sp, st);
    y = fmaf(Dv, xcv, y);
    xc_yg[m*DI + d] = y * (zv * sigmoidf_(zv));
  }
}

extern "C" void kernel_launch(void* const* d_in, const int* in_sizes, int n_in,
                              void* d_out, int out_size, void* d_ws, size_t ws_size,
                              hipStream_t stream)
{
  const float* x        = (const float*)d_in[0];
  const float* in_w     = (const float*)d_in[1];
  const float* conv_w   = (const float*)d_in[2];
  const float* conv_b   = (const float*)d_in[3];
  const float* xproj_w  = (const float*)d_in[4];
  const float* dtproj_w = (const float*)d_in[5];
  const float* dtproj_b = (const float*)d_in[6];
  const float* A_log    = (const float*)d_in[7];
  const float* Dp       = (const float*)d_in[8];
  const float* out_w    = (const float*)d_in[9];

  float* out0 = (float*)d_out;                       // outputs  [B,L,DM]
  float* out1 = out0 + (size_t)B_*L_*DM;             // out_traj [L,B,DM]
  float* out2 = out1 + (size_t)B_*L_*DM;             // conv_traj [L+1,B,DI,DC]
  float* out3 = out2 + (size_t)(L_+1)*B_*DI*DC;      // ssm_traj  [L+1,B,DI,DS]

  float* ws   = (float*)d_ws;
  float* xz   = ws;                                  // [4096][4096]; later cols 0..2047 reused for dt
  float* xc   = xz + (size_t)NROWS*2*DI;             // [4096][2048]; later holds yg in-place
  float* xdb  = xc + (size_t)NROWS*DI;               // [4096][96]
  float* Ssum = xdb + (size_t)NROWS*96;              // [B_*NC][DI]
  float* Qbuf = Ssum + (size_t)B_*NC*DI;             // [B_*NC][DI][DS]

  // zero init: conv_traj[0], ssm_traj[0], xdb (split-K atomic target)
  hipLaunchKernelGGL(zero_f32, dim3((B_*DI*DC+255)/256), dim3(256), 0, stream, out2, B_*DI*DC);
  hipLaunchKernelGGL(zero_f32, dim3((B_*DI*DS+255)/256), dim3(256), 0, stream, out3, B_*DI*DS);
  hipLaunchKernelGGL(zero_f32, dim3((NROWS*96+255)/256), dim3(256), 0, stream, xdb, NROWS*96);

  // G1: xz = X @ in_proj_w^T   (4096 x 4096 x 1024)
  hipLaunchKernelGGL((gemm_nt<128,128,8,0>), dim3(4096/128, 4096/128, 1), dim3(256), 0, stream,
                     x, in_w, xz, (float*)nullptr, (const float*)nullptr, 4096, 4096, 1024, 1024, 4096);

  // conv + silu + conv_traj
  hipLaunchKernelGGL(conv_silu, dim3(NROWS*DI/256), dim3(256), 0, stream, xz, conv_w, conv_b, xc, out2);

  // G2: xdb = xc @ x_proj_w^T  (4096 x 96 x 2048), split-K=4 via atomicAdd
  hipLaunchKernelGGL((gemm_nt<64,64,16,3>), dim3(2, 4096/64, 4), dim3(256), 0, stream,
                     xc, xproj_w, xdb, (float*)nullptr, (const float*)nullptr, 4096, 96, 2048, 2048, 96);

  // G3: dt = softplus(xdb[:,:64] @ dt_proj_w^T + b) -> xz cols [0,2048) (ldc=4096)
  hipLaunchKernelGGL((gemm_nt<128,128,8,1>), dim3(2048/128, 4096/128, 1), dim3(256), 0, stream,
                     xdb, dtproj_w, xz, (float*)nullptr, dtproj_b, 4096, 2048, 64, 96, 4096);

  // chunked parallel scan (3 phases)
  hipLaunchKernelGGL(scan_phase1, dim3(B_*NC*DI/256), dim3(256), 0, stream,
                     xz, xc, xdb, A_log, Ssum, Qbuf);
  hipLaunchKernelGGL(scan_phase2, dim3(B_*DI*DS/256), dim3(256), 0, stream,
                     Ssum, Qbuf, A_log);
  hipLaunchKernelGGL(scan_phase3, dim3(B_*NC*DI/256), dim3(256), 0, stream,
                     xz, xc, xdb, A_log, Dp, Qbuf, out3);

  // G4: out = yg @ out_proj_w^T (4096 x 1024 x 2048), dual store outputs + out_traj
  hipLaunchKernelGGL((gemm_nt<128,128,8,2>), dim3(1024/128, 4096/128, 1), dim3(256), 0, stream,
                     xc, out_w, out0, out1, (const float*)nullptr, 4096, 1024, 2048, 2048, 1024);
}